// Round 3
// baseline (179.614 us; speedup 1.0000x reference)
//
#include <hip/hip_runtime.h>
#include <math.h>

// Problem: SphericalHarmonicTransform, L=8, RCUT=5, N=4194304 points.
// out[81] = sum over points of (modified) solid harmonic terms.
// R12: 2-point manual interleave via f32x4 (pt0.z1, pt0.z2, pt1.z1, pt1.z2).
//     R11 killed the register-cap theory: with (256,1) free budget, allocator
//     CHOSE 108 VGPR and scheduled the 8 point bodies serially -> 0.38 VALU
//     instr/cyc/CU vs 2.0 ceiling (19%), VALUBusy 47%. The f32x2 ops compile
//     to v_pk_fma_f32, making z-chains and p-sums SERIAL packed dep chains
//     (4-5cy latency vs 2cy issue). Compiler refuses cross-point interleave;
//     force it at source: every chain/sum op is f32x4 = 2 independent
//     v_pk_fma_f32. Same per-point instr count, 2x ILP. ext_vector components
//     are plain VGPRs - no pack/extract instrs (R8's failure mode avoided).
//     Accumulation order-preserving: pt0 folded before pt1, bit-identical to
//     two sequential point_body calls.
//     Predicted: VGPR 170-240, WRITE_SIZE ~2.6MB (spill guard), VALUBusy
//     60-80%, sht_main 75 -> 48-60us. If neutral: issue-bound -> pivot to
//     instruction-count reduction (m-split two-pass).
// Known-bad: launch_bounds(256,4) -> VGPR 64 clamp -> 1.1GB spill (R2);
//     waves_per_eu(2,2) -> 128 clamp + spill, 160us (R10); min-waves {1,2}
//     identical 75us (R9/R11) -> TLP not the lever; fused finalize (R5);
//     per-point prefetch (R4); pack/extract-heavy f32x2 reshape (R8, 26%).

typedef float f32x2 __attribute__((ext_vector_type(2)));
typedef float f32x4 __attribute__((ext_vector_type(4)));

#define NL 8               // L
#define NBLK 1024
#define NTHR 256

__device__ __forceinline__ f32x2 sp(float v) { return f32x2{v, v}; }
__device__ __forceinline__ f32x4 sp4(float v) { return f32x4{v, v, v, v}; }

__device__ __forceinline__ f32x2 pkfma(f32x2 a, f32x2 b, f32x2 c) {
    return __builtin_elementwise_fma(a, b, c);
}
__device__ __forceinline__ f32x4 pkfma4(f32x4 a, f32x4 b, f32x4 c) {
    return __builtin_elementwise_fma(a, b, c);
}

__device__ __forceinline__ float waveReduce(float v) {
    v += __shfl_down(v, 32);
    v += __shfl_down(v, 16);
    v += __shfl_down(v, 8);
    v += __shfl_down(v, 4);
    v += __shfl_down(v, 2);
    v += __shfl_down(v, 1);
    return v;
}

// Two points, fully unrolled, arithmetic bit-identical to two sequential
// single-point bodies (pt A folded into accumulators before pt B).
// Lane packing for chains: {A.z1, A.z2, B.z1, B.z2}.
__device__ __forceinline__ void point_pair_body(
        float xA, float yA, float zA,
        float xB, float yB, float zB,
        float* __restrict__ acc0, f32x2* __restrict__ accp) {
    const float FACT[9] = {1.f, 1.f, 2.f, 6.f, 24.f, 120.f, 720.f, 5040.f, 40320.f};

    // ---- per-point prologue (scalar; small) ----
    float invA, x0cA;
    {
        const float r2 = xA * xA + yA * yA + zA * zA;
        const bool valid = r2 > 0.0f;
        const float iv0 = __builtin_amdgcn_rsqf(r2);
        const float norm = r2 * iv0;                   // NaN at 0, masked below
        float cut = 0.5f * (__cosf(norm * 0.6283185307179586f) + 1.0f);
        cut = (r2 > 25.0f) ? 0.0f : cut;
        cut = valid ? cut : 0.0f;
        invA = valid ? iv0 : 1.0f;
        x0cA = zA * cut;
    }
    float invB, x0cB;
    {
        const float r2 = xB * xB + yB * yB + zB * zB;
        const bool valid = r2 > 0.0f;
        const float iv0 = __builtin_amdgcn_rsqf(r2);
        const float norm = r2 * iv0;
        float cut = 0.5f * (__cosf(norm * 0.6283185307179586f) + 1.0f);
        cut = (r2 > 25.0f) ? 0.0f : cut;
        cut = valid ? cut : 0.0f;
        invB = valid ? iv0 : 1.0f;
        x0cB = zB * cut;
    }

    // ---- packed chains: {A.z1, A.z2, B.z1, B.z2} ----
    const f32x4 w  = { -0.5f * xA,  0.5f * xA, -0.5f * xB,  0.5f * xB };
    const f32x4 wi = { -0.5f * yA, -0.5f * yA, -0.5f * yB, -0.5f * yB };

    // powcmplx replication (same buggy chain as reference):
    //  n=0 -> (1,0); n=1 -> w; n=2 -> special (r^2-i^2, 2ri);
    //  n>=3 -> nr = wr*br - wi*bi; ni = wr*bi + wi*nr (uses NEW nr).
    f32x4 zr[9], zi[9];
    zr[0] = sp4(1.f); zi[0] = sp4(0.f);
    zr[1] = w;        zi[1] = wi;
    zr[2] = w * w - wi * wi;
    zi[2] = (w + w) * wi;
    {
        f32x4 cr = zr[2];
        f32x4 ci = w * wi + wi * cr;                   // buggy chain imag at k=2
#pragma unroll
        for (int k = 3; k <= NL; ++k) {
            const f32x4 nr = w * cr - wi * ci;
            const f32x4 ni = w * ci + wi * nr;         // buggy: uses nr
            cr = nr; ci = ni;
            zr[k] = nr; zi[k] = ni;
        }
    }

    // unpack views (register aliases, free)
    float aa0[9], bb0[9], cc0[9], dd0[9], sqa0[9];
    float aa1[9], bb1[9], cc1[9], dd1[9], sqa1[9];
#pragma unroll
    for (int p = 0; p <= NL; ++p) {
        aa0[p] = zr[p].x;  cc0[p] = zr[p].y;
        aa1[p] = zr[p].z;  cc1[p] = zr[p].w;
        bb0[p] = zi[p].x;  dd0[p] = zi[p].y;
        bb1[p] = zi[p].z;  dd1[p] = zi[p].w;
        sqa0[p] = aa0[p] * aa0[p];
        sqa1[p] = aa1[p] * aa1[p];
    }

    // h_l = x0c * inv^l, packed {A, B}
    f32x2 h[9];
    h[0] = f32x2{x0cA, x0cB};
    const f32x2 iv2 = {invA, invB};
#pragma unroll
    for (int l = 1; l <= NL; ++l) h[l] = h[l - 1] * iv2;

    // ---- m = 0: pure-real, packed over the pair ----
    {
        f32x2 Y0[5];                                    // p = q, p <= 4
#pragma unroll
        for (int p = 0; p <= 4; ++p) {
            const float cpq = 1.0f / (FACT[p] * FACT[p]);       // compile-time
            const f32x2 D = { dd0[p], dd1[p] };
            const f32x2 S = { sqa0[p], sqa1[p] };
            Y0[p] = pkfma(-D, D, S) * sp(cpq);
        }
#pragma unroll
        for (int l = 0; l <= NL; ++l) {
            f32x2 sr = sp(0.f);
#pragma unroll
            for (int p = 0; p <= 4; ++p) {
                if (2 * p <= l) {
                    const float is = 1.0f / FACT[l - 2 * p];    // 9 uniques
                    sr = pkfma(Y0[p], sp(is), sr);
                }
            }
            // order-preserving: pt A then pt B
            acc0[l] = fmaf(sr.x, h[l].x, acc0[l]);
            acc0[l] = fmaf(sr.y, h[l].y, acc0[l]);
        }
    }

    // ---- m >= 1: packed {A.re, A.im, B.re, B.im} ----
#pragma unroll
    for (int m = 1; m <= NL; ++m) {
        f32x4 Y[9];
#pragma unroll
        for (int p = 0; p <= NL; ++p) {
            if (p >= m && 2 * p - m <= NL) {
                const int q = p - m;
                const float cpq = 1.0f / (FACT[p] * FACT[q]);   // compile-time
                const f32x4 A = { -dd0[q], aa0[p], -dd1[q], aa1[p] };
                const f32x4 B = {  dd0[q], dd0[q],  dd1[q], dd1[q] };
                const f32x4 C = { sqa0[p], bb0[p] * cc0[q],
                                  sqa1[p], bb1[p] * cc1[q] };
                Y[p] = pkfma4(A, B, C) * sp4(cpq);
            }
        }
#pragma unroll
        for (int l = m; l <= NL; ++l) {
            f32x4 s = sp4(0.f);
#pragma unroll
            for (int p = 0; p <= NL; ++p) {
                if (p >= m && 2 * p - m <= l) {
                    const float is = 1.0f / FACT[l - 2 * p + m]; // 9 uniques
                    s = pkfma4(Y[p], sp4(is), s);
                }
            }
            // accp index: t(l,m) = l*(l-1)/2 + (m-1)
            const int ai = l * (l - 1) / 2 + (m - 1);
            // order-preserving: pt A folded before pt B
            const f32x2 slo = { s.x, s.y };
            const f32x2 shi = { s.z, s.w };
            accp[ai] = pkfma(slo, sp(h[l].x), accp[ai]);
            accp[ai] = pkfma(shi, sp(h[l].y), accp[ai]);
        }
    }
}

__global__ __launch_bounds__(256, 1)
void sht_main(const float* __restrict__ pos, float* __restrict__ ws, int n) {
    float acc0[9];
    f32x2 accp[36];
#pragma unroll
    for (int i = 0; i < 9; ++i) acc0[i] = 0.f;
#pragma unroll
    for (int i = 0; i < 36; ++i) accp[i] = sp(0.f);

    const int t = blockIdx.x * NTHR + threadIdx.x;
    const int nthreads = NBLK * NTHR;                       // 262144
    const int nchunks = (n / 8 + nthreads - 1) / nthreads;  // 2 for N=2^22

    for (int c = 0; c < nchunks; ++c) {
        const int idx = (c * nthreads + t) * 8;             // 8 contiguous points
        float xs[8], ys[8], zs[8];
        if (idx + 8 <= n) {
            // 6x float4 = 96B, 16B-aligned (idx%8==0 -> offset multiple of 96B)
            const float4* p4 = reinterpret_cast<const float4*>(pos + (size_t)3 * idx);
            const float4 q0 = p4[0], q1 = p4[1], q2 = p4[2];
            const float4 q3 = p4[3], q4 = p4[4], q5 = p4[5];
            xs[0] = q0.x; ys[0] = q0.y; zs[0] = q0.z;
            xs[1] = q0.w; ys[1] = q1.x; zs[1] = q1.y;
            xs[2] = q1.z; ys[2] = q1.w; zs[2] = q2.x;
            xs[3] = q2.y; ys[3] = q2.z; zs[3] = q2.w;
            xs[4] = q3.x; ys[4] = q3.y; zs[4] = q3.z;
            xs[5] = q3.w; ys[5] = q4.x; zs[5] = q4.y;
            xs[6] = q4.z; ys[6] = q4.w; zs[6] = q5.x;
            xs[7] = q5.y; ys[7] = q5.z; zs[7] = q5.w;
        } else {
#pragma unroll
            for (int k = 0; k < 8; ++k) {
                const int i = idx + k;
                const bool ok = i < n;
                xs[k] = ok ? pos[3 * i + 0] : 0.f;          // zero-pad: contributes 0
                ys[k] = ok ? pos[3 * i + 1] : 0.f;
                zs[k] = ok ? pos[3 * i + 2] : 0.f;
            }
        }
#pragma unroll
        for (int k = 0; k < 8; k += 2)
            point_pair_body(xs[k], ys[k], zs[k],
                            xs[k + 1], ys[k + 1], zs[k + 1], acc0, accp);
    }

    // ---- reduction: wave shuffle -> LDS across 4 waves -> per-block row ----
    __shared__ float red[81][5];   // [out slot][wave], padded stride
    const int lane = threadIdx.x & 63;
    const int wave = threadIdx.x >> 6;

#pragma unroll
    for (int l = 0; l <= NL; ++l) {
        float vr = waveReduce(acc0[l]);
        if (lane == 0) red[l * l + l][wave] = vr;
    }
#pragma unroll
    for (int m = 1; m <= NL; ++m) {
#pragma unroll
        for (int l = m; l <= NL; ++l) {
            const int ai = l * (l - 1) / 2 + (m - 1);
            float vr = waveReduce(accp[ai].x);
            if (lane == 0) red[l * l + l + m][wave] = vr;
            float vi = waveReduce(accp[ai].y);
            if (lane == 0) red[l * l + l - m][wave] = vi;
        }
    }
    __syncthreads();

    // transposed partials: ws[slot*NBLK + block] -> coalesced finalize reads
    if ((int)threadIdx.x < 81) {
        float s = 0.f;
#pragma unroll
        for (int w = 0; w < 4; ++w) s += red[threadIdx.x][w];
        ws[(size_t)threadIdx.x * NBLK + blockIdx.x] = s;
    }
}

__device__ double dfact(int nn) {
    double r = 1.0;
    for (int i = 2; i <= nn; ++i) r *= (double)i;
    return r;
}

// one block per output slot; 256 threads sum 1024 coalesced partials
__global__ __launch_bounds__(256)
void sht_finalize(const float* __restrict__ ws, float* __restrict__ out) {
    const int j = blockIdx.x;       // 0..80
    const int t = threadIdx.x;
    float s = 0.f;
#pragma unroll
    for (int k = 0; k < NBLK / 256; ++k)
        s += ws[(size_t)j * NBLK + k * 256 + t];
    s = waveReduce(s);

    __shared__ float red[4];
    const int lane = t & 63, wave = t >> 6;
    if (lane == 0) red[wave] = s;
    __syncthreads();
    if (t == 0) {
        float tot = red[0] + red[1] + red[2] + red[3];
        int l = 0;
        while ((l + 1) * (l + 1) <= j) ++l;
        const int M = j - l * l - l;
        const int m = (M < 0) ? -M : M;
        // f = sqrt((l+m)!(l-m)!); k_l = sqrt((2l+1)/(4*3.14159))  (ref PI=3.14159)
        double sc = sqrt(dfact(l + m) * dfact(l - m)) *
                    sqrt((double)(2 * l + 1) / (4.0 * 3.14159));
        if (m > 0) sc *= sqrt(2.0) * ((m & 1) ? -1.0 : 1.0);
        out[j] = (float)((double)tot * sc);
    }
}

extern "C" void kernel_launch(void* const* d_in, const int* in_sizes, int n_in,
                              void* d_out, int out_size, void* d_ws, size_t ws_size,
                              hipStream_t stream) {
    const float* pos = (const float*)d_in[0];
    const int npts = in_sizes[0] / 3;
    float* ws = (float*)d_ws;
    float* out = (float*)d_out;

    sht_main<<<NBLK, NTHR, 0, stream>>>(pos, ws, npts);
    sht_finalize<<<81, 256, 0, stream>>>(ws, out);
}

// Round 5
// 133.108 us; speedup vs baseline: 1.3494x; 1.3494x over previous
//
#include <hip/hip_runtime.h>
#include <math.h>

// Problem: SphericalHarmonicTransform, L=8, RCUT=5, N=4194304 points.
// out[81] = sum over points of (modified) solid harmonic terms.
// R14 == R13 resubmitted (round 4 was an infra failure: "container failed
//     twice" - no compile/correctness/timing data came back; the kernel is a
//     strict un-unroll of the many-times-passed R9, so nothing to revise).
// R13: un-unroll the point loop (8-body -> 1-body, #pragma unroll 1).
//     Theory pivot: kernel is L1I-FETCH-bound, not dep-chain-bound.
//     Evidence: (1) prior model "time ~ static instr count" = fetch signature;
//     (2) occupancy knobs no-op (waves all miss same I$) but REMOVING waves
//     hurts linearly (R12: dur ~ 1/occ, VALUBusy ~ occ); (3) issue rate 0.38
//     instr/cyc/CU vs 2.0 capacity with VALUBusy pinned ~47%; (4) 8-point
//     unrolled body ~20-40KB vs 32KB L1I; R8/R12 grew the body and regressed
//     proportionally. This round: per-point loop body (~3-5KB, I$-resident),
//     SAME per-point arithmetic and SAME point order per thread (bit-identical,
//     absmax 0.0 expected). Loads become per-point dwordx3; consecutive k hit
//     the same cache lines -> HBM traffic unchanged.
//     Predicted: if I$-bound: sht_main 75 -> 45-60us, VALUBusy -> 60-80%.
//     If latency-bound instead: ~80-85us (lost cross-point sched) -> revert &
//     pivot to instruction-count reduction inside the body.
// Known-bad: launch_bounds(256,4) -> VGPR 64 clamp -> 1.1GB spill (R2);
//     waves_per_eu(2,2) -> 128 clamp + spill, 160us (R10); min-waves {1,2}
//     identical 75us (R9/R11) -> TLP knob dead; f32x4 2-pt interleave -> +44
//     VGPR, no IPC gain, 119us (R12); pack/extract f32x2 reshape (R8, 26%);
//     fused finalize (R5); per-point prefetch (R4).

typedef float f32x2 __attribute__((ext_vector_type(2)));

#define NL 8               // L
#define NBLK 1024
#define NTHR 256

__device__ __forceinline__ f32x2 sp(float v) { return f32x2{v, v}; }

__device__ __forceinline__ f32x2 pkfma(f32x2 a, f32x2 b, f32x2 c) {
    return __builtin_elementwise_fma(a, b, c);
}

__device__ __forceinline__ float waveReduce(float v) {
    v += __shfl_down(v, 32);
    v += __shfl_down(v, 16);
    v += __shfl_down(v, 8);
    v += __shfl_down(v, 4);
    v += __shfl_down(v, 2);
    v += __shfl_down(v, 1);
    return v;
}

// One point, fully unrolled. acc0 = m=0 reals (9); accp = m>=1 (re,im) pairs (36).
// Arithmetic identical to R9 (bit-exact per-point contributions).
__device__ __forceinline__ void point_body(float x, float y, float z,
                                           float* __restrict__ acc0,
                                           f32x2* __restrict__ accp) {
    const float FACT[9] = {1.f, 1.f, 2.f, 6.f, 24.f, 120.f, 720.f, 5040.f, 40320.f};

    const float r2 = x * x + y * y + z * z;
    const bool valid = r2 > 0.0f;
    const float inv0 = __builtin_amdgcn_rsqf(r2);      // 1/sqrt(r2)
    const float norm = r2 * inv0;                      // sqrt(r2); NaN at 0, masked
    float cut = 0.5f * (__cosf(norm * 0.6283185307179586f) + 1.0f);
    cut = (r2 > 25.0f) ? 0.0f : cut;
    cut = valid ? cut : 0.0f;                          // kills NaN at r2=0
    const float inv = valid ? inv0 : 1.0f;             // safe 1/norm
    const float x0c = z * cut;

    // packed chains: lane0 = z1 (xp), lane1 = z2 (xm)
    const f32x2 w  = { -0.5f * x,  0.5f * x };         // (xpr, xmr)
    const f32x2 wi = { -0.5f * y, -0.5f * y };         // (xpi, xmi)

    // powcmplx replication:
    //  n=0 -> (1,0); n=1 -> w; n=2 -> special (r^2-i^2, 2ri);
    //  n>=3 -> buggy chain: nr = wr*br - wi*bi; ni = wr*bi + wi*nr (uses NEW nr)
    //  chain's k=2 real == special real; its (buggy) imag feeds k>=3.
    f32x2 zr[9], zi[9];
    zr[0] = sp(1.f); zi[0] = sp(0.f);
    zr[1] = w;       zi[1] = wi;
    zr[2] = w * w - wi * wi;
    zi[2] = (w + w) * wi;                              // 2*wr*wi
    {
        f32x2 cr = zr[2];
        f32x2 ci = w * wi + wi * cr;                   // buggy chain imag at k=2
#pragma unroll
        for (int k = 3; k <= NL; ++k) {
            const f32x2 nr = w * cr - wi * ci;
            const f32x2 ni = w * ci + wi * nr;         // buggy: uses nr
            cr = nr; ci = ni;
            zr[k] = nr; zi[k] = ni;
        }
    }

    // unpack views (register aliases, free)
    float aa[9], bb[9], cc[9], dd[9], sqa[9];
#pragma unroll
    for (int p = 0; p <= NL; ++p) {
        aa[p] = zr[p].x;   // z1r
        cc[p] = zr[p].y;   // z2r
        bb[p] = zi[p].x;   // z1i
        dd[p] = zi[p].y;   // z2i
        sqa[p] = aa[p] * aa[p];
    }

    // h_l = x0c * inv^l  (cutoff + 1/r^l deferred out of the sums)
    float h[9];
    h[0] = x0c;
#pragma unroll
    for (int l = 1; l <= NL; ++l) h[l] = h[l - 1] * inv;

    // ---- m = 0: pure-real scalar path (no dead imag work) ----
    {
        float Y0[5];                                    // p = q, p <= 4
#pragma unroll
        for (int p = 0; p <= 4; ++p) {
            const float cpq = 1.0f / (FACT[p] * FACT[p]);       // compile-time
            Y0[p] = fmaf(-dd[p], dd[p], sqa[p]) * cpq;
        }
#pragma unroll
        for (int l = 0; l <= NL; ++l) {
            float sr = 0.f;
#pragma unroll
            for (int p = 0; p <= 4; ++p) {
                if (2 * p <= l) {
                    const float is = 1.0f / FACT[l - 2 * p];    // 9 uniques
                    sr = fmaf(Y0[p], is, sr);
                }
            }
            acc0[l] = fmaf(sr, h[l], acc0[l]);
        }
    }

    // ---- m >= 1: packed (real, imag) ----
#pragma unroll
    for (int m = 1; m <= NL; ++m) {
        f32x2 Y[9];
#pragma unroll
        for (int p = 0; p <= NL; ++p) {
            if (p >= m && 2 * p - m <= NL) {
                const int q = p - m;
                const float cpq = 1.0f / (FACT[p] * FACT[q]);   // compile-time
                const float bc = bb[p] * cc[q];
                const f32x2 A = { -dd[q], aa[p] };
                const f32x2 B = {  dd[q], dd[q] };
                const f32x2 C = { sqa[p], bc };
                Y[p] = pkfma(A, B, C) * sp(cpq);
            }
        }
#pragma unroll
        for (int l = m; l <= NL; ++l) {
            f32x2 s = sp(0.f);
#pragma unroll
            for (int p = 0; p <= NL; ++p) {
                if (p >= m && 2 * p - m <= l) {
                    const float is = 1.0f / FACT[l - 2 * p + m]; // 9 uniques
                    s = pkfma(Y[p], sp(is), s);
                }
            }
            // accp index: t(l,m) = l*(l-1)/2 + (m-1)
            const int ai = l * (l - 1) / 2 + (m - 1);
            accp[ai] = pkfma(s, sp(h[l]), accp[ai]);
        }
    }
}

__global__ __launch_bounds__(256, 1)
void sht_main(const float* __restrict__ pos, float* __restrict__ ws, int n) {
    float acc0[9];
    f32x2 accp[36];
#pragma unroll
    for (int i = 0; i < 9; ++i) acc0[i] = 0.f;
#pragma unroll
    for (int i = 0; i < 36; ++i) accp[i] = sp(0.f);

    const int t = blockIdx.x * NTHR + threadIdx.x;
    const int nthreads = NBLK * NTHR;                       // 262144
    const int nchunks = (n / 8 + nthreads - 1) / nthreads;  // 2 for N=2^22

    // Same ownership & order as R9 (thread owns 8 contiguous points per chunk,
    // processed in order) -> bit-identical accumulation. Only the UNROLL
    // changed: one point per iteration keeps the hot body I$-resident.
    for (int c = 0; c < nchunks; ++c) {
        const int idx = (c * nthreads + t) * 8;             // 8 contiguous points
#pragma unroll 1
        for (int k = 0; k < 8; ++k) {
            const int i = idx + k;
            float x, y, z;
            if (i < n) {
                x = pos[3 * i + 0];                         // dwordx3; k and k+1
                y = pos[3 * i + 1];                         // share cache lines
                z = pos[3 * i + 2];
            } else {
                x = 0.f; y = 0.f; z = 0.f;                  // zero-pad: adds 0
            }
            point_body(x, y, z, acc0, accp);
        }
    }

    // ---- reduction: wave shuffle -> LDS across 4 waves -> per-block row ----
    __shared__ float red[81][5];   // [out slot][wave], padded stride
    const int lane = threadIdx.x & 63;
    const int wave = threadIdx.x >> 6;

#pragma unroll
    for (int l = 0; l <= NL; ++l) {
        float vr = waveReduce(acc0[l]);
        if (lane == 0) red[l * l + l][wave] = vr;
    }
#pragma unroll
    for (int m = 1; m <= NL; ++m) {
#pragma unroll
        for (int l = m; l <= NL; ++l) {
            const int ai = l * (l - 1) / 2 + (m - 1);
            float vr = waveReduce(accp[ai].x);
            if (lane == 0) red[l * l + l + m][wave] = vr;
            float vi = waveReduce(accp[ai].y);
            if (lane == 0) red[l * l + l - m][wave] = vi;
        }
    }
    __syncthreads();

    // transposed partials: ws[slot*NBLK + block] -> coalesced finalize reads
    if ((int)threadIdx.x < 81) {
        float s = 0.f;
#pragma unroll
        for (int w = 0; w < 4; ++w) s += red[threadIdx.x][w];
        ws[(size_t)threadIdx.x * NBLK + blockIdx.x] = s;
    }
}

__device__ double dfact(int nn) {
    double r = 1.0;
    for (int i = 2; i <= nn; ++i) r *= (double)i;
    return r;
}

// one block per output slot; 256 threads sum 1024 coalesced partials
__global__ __launch_bounds__(256)
void sht_finalize(const float* __restrict__ ws, float* __restrict__ out) {
    const int j = blockIdx.x;       // 0..80
    const int t = threadIdx.x;
    float s = 0.f;
#pragma unroll
    for (int k = 0; k < NBLK / 256; ++k)
        s += ws[(size_t)j * NBLK + k * 256 + t];
    s = waveReduce(s);

    __shared__ float red[4];
    const int lane = t & 63, wave = t >> 6;
    if (lane == 0) red[wave] = s;
    __syncthreads();
    if (t == 0) {
        float tot = red[0] + red[1] + red[2] + red[3];
        int l = 0;
        while ((l + 1) * (l + 1) <= j) ++l;
        const int M = j - l * l - l;
        const int m = (M < 0) ? -M : M;
        // f = sqrt((l+m)!(l-m)!); k_l = sqrt((2l+1)/(4*3.14159))  (ref PI=3.14159)
        double sc = sqrt(dfact(l + m) * dfact(l - m)) *
                    sqrt((double)(2 * l + 1) / (4.0 * 3.14159));
        if (m > 0) sc *= sqrt(2.0) * ((m & 1) ? -1.0 : 1.0);
        out[j] = (float)((double)tot * sc);
    }
}

extern "C" void kernel_launch(void* const* d_in, const int* in_sizes, int n_in,
                              void* d_out, int out_size, void* d_ws, size_t ws_size,
                              hipStream_t stream) {
    const float* pos = (const float*)d_in[0];
    const int npts = in_sizes[0] / 3;
    float* ws = (float*)d_ws;
    float* out = (float*)d_out;

    sht_main<<<NBLK, NTHR, 0, stream>>>(pos, ws, npts);
    sht_finalize<<<81, 256, 0, stream>>>(ws, out);
}